// Round 13
// baseline (146.832 us; speedup 1.0000x reference)
//
#include <hip/hip_runtime.h>
#include <hip/hip_bf16.h>
#include <math.h>

// ---------------- problem constants ----------------
constexpr int BS   = 512;
constexpr int NBS  = 1536;   // BS * NSENT
constexpr int NPOS = 300;    // HIST*H*W
constexpr int LIN  = 5184;   // FM * 9 * 9
constexpr int KSPLIT = 9, KCH = 576;    // 9*576 = 5184

typedef __attribute__((ext_vector_type(8))) short bf16x8;
typedef __attribute__((ext_vector_type(4))) float f32x4;

static __device__ __forceinline__ short f2bf(float f) {
    unsigned u = __float_as_uint(f);
    unsigned r = (u + 0x7FFFu + ((u >> 16) & 1u)) >> 16;
    return (short)r;
}
static __device__ __forceinline__ unsigned pk2(float a, float b) {
    return ((unsigned)(unsigned short)f2bf(a)) | (((unsigned)(unsigned short)f2bf(b)) << 16);
}
static __device__ __forceinline__ float bf2f_lo(unsigned u) { return __uint_as_float(u << 16); }
static __device__ __forceinline__ float bf2f_hi(unsigned u) { return __uint_as_float(u & 0xFFFF0000u); }

#define DOT4(a,b) ((a).x*(b).x + (a).y*(b).y + (a).z*(b).z + (a).w*(b).w)

// ---------------- workspace layout (float offsets) ----------------
constexpr size_t OFF_RD   = 0;         // 26*768 fp32 (0..24 rowdot, 25 = bv@W2)
constexpr size_t OFF_FL   = 19968;     // 64 (int)
constexpr size_t OFF_DT   = 20032;     // fp32 [1536][64]
constexpr size_t OFF_WCT  = 118336;    // bf16 [768][768] -> 294912 floats
constexpr size_t OFF_PH   = 413248;    // bf16 [64][768]  -> 24576
constexpr size_t OFF_AB   = 437824;    // bf16 [256][5184] -> 663552
constexpr size_t OFF_XKH  = 1322560;   // bf16 [1536][768] -> 589824 floats
constexpr size_t OFF_XVH  = 1912384;   // bf16 [1536][768] -> 589824
constexpr size_t OFF_VWH  = 2502208;   // bf16 [1536][768] -> 589824
constexpr size_t OFF_YH   = 3092032;   // bf16 [512][5184] -> 1327104 floats
constexpr size_t OFF_PART = 4419136;   // fp32 [9][512][256]; end 5598784 (~22.4MB)

// ======== k1: monolithic per-(b,s) temb, 1024 threads, 2 blocks/CU ===========
// blocks 0..1535 : (b,s): stage all 36 tokens as bf16 in LDS (read temb ONCE),
//                  scores -> softmax -> 2-way-split weighted sums -> XKH/XVH.
// blocks 1536+   : prep (AB 0..323, PH 324..342, RD 343..362, WCT 363..506, FL 507)
__global__ __launch_bounds__(1024) void k1_fused(
    const float* __restrict__ temb, const float* __restrict__ Wks,
    const float* __restrict__ Wvs, const float* __restrict__ conv_w,
    const float* __restrict__ sprite, const float* __restrict__ Wk,
    const float* __restrict__ Wv, const float* __restrict__ bv,
    const float* __restrict__ a1, const float* __restrict__ v1,
    short* __restrict__ XKH, short* __restrict__ XVH,
    short* __restrict__ AB, short* __restrict__ PH, short* __restrict__ WCT,
    float* __restrict__ RD, int* __restrict__ FL)
{
    __shared__ unsigned smem[15520];   // 13824 hbuf + 160 sco + 1536 red = 62.1KB -> 2 blocks/CU
    unsigned* hbuf = smem;
    float (*sco)[40] = (float(*)[40])(smem + 13824);
    float* red = (float*)(smem + 13984);           // [4][384]
    int tid = threadIdx.x, bx = blockIdx.x;
    int w = tid >> 6, lane = tid & 63;

    if (bx < NBS) {
        int bs = bx;
        const f32x4* src4 = (const f32x4*)temb + (size_t)bs * 6912;

        // ---- phase 1: stage all 36 tokens (6912 float4) as bf16 ----
        #pragma unroll
        for (int c = 0; c < 7; ++c) {
            int i = c * 1024 + tid;
            if (c < 6 || tid < 768) {
                f32x4 v = src4[i];
                hbuf[2 * i]     = pk2(v.x, v.y);
                hbuf[2 * i + 1] = pk2(v.z, v.w);
            }
        }
        __syncthreads();

        // ---- phase 2: scores (16 waves cover 36 tokens in 2.25 rounds) ----
        const float2* wks2 = (const float2*)Wks;
        const float2* wvs2 = (const float2*)Wvs;
        #pragma unroll
        for (int r = 0; r < 3; ++r) {
            int t = w + 16 * r;
            if (r < 2 || w < 4) {
                float pk = 0.f, pv = 0.f;
                #pragma unroll
                for (int j = 0; j < 6; ++j) {
                    unsigned u = hbuf[t * 384 + lane + 64 * j];
                    float x0 = bf2f_lo(u), x1 = bf2f_hi(u);
                    float2 a = wks2[lane + 64 * j];
                    float2 b = wvs2[lane + 64 * j];
                    pk += x0 * a.x + x1 * a.y;
                    pv += x0 * b.x + x1 * b.y;
                }
                #pragma unroll
                for (int off = 32; off; off >>= 1) {
                    pk += __shfl_down(pk, off);
                    pv += __shfl_down(pv, off);
                }
                if (lane == 0) { sco[0][t] = pk; sco[1][t] = pv; }
            }
        }
        __syncthreads();

        // ---- phase 3: exact softmax over 36 (waves 0,1 for k,v) ----
        if (w < 2) {
            float s = (lane < 36) ? sco[w][lane] : -INFINITY;
            float m = s;
            #pragma unroll
            for (int off = 32; off; off >>= 1) m = fmaxf(m, __shfl_xor(m, off));
            float e = (lane < 36) ? expf(s - m) : 0.f;
            float z = e;
            #pragma unroll
            for (int off = 32; off; off >>= 1) z += __shfl_xor(z, off);
            if (lane < 36) sco[2 + w][lane] = e / z;
        }
        __syncthreads();

        // ---- phase 4: weighted sums, 2-way token split (768 threads) ----
        float k0 = 0.f, k1 = 0.f, v0 = 0.f, v1 = 0.f;
        int g = tid >> 9;            // wait: need tid/384 split
        g = tid / 384;               // 0,1 for tid<768
        int c = tid - g * 384;
        if (tid < 768) {
            int t0 = g * 18;
            #pragma unroll
            for (int tt = 0; tt < 18; ++tt) {
                int t = t0 + tt;
                unsigned u = hbuf[t * 384 + c];
                float x0 = bf2f_lo(u), x1 = bf2f_hi(u);
                float wk = sco[2][t], wv = sco[3][t];
                k0 += wk * x0; k1 += wk * x1;
                v0 += wv * x0; v1 += wv * x1;
            }
            if (g == 1) {
                red[c]        = k0;
                red[384 + c]  = k1;
                red[768 + c]  = v0;
                red[1152 + c] = v1;
            }
        }
        __syncthreads();
        if (tid < 384) {
            k0 += red[tid];
            k1 += red[384 + tid];
            v0 += red[768 + tid];
            v1 += red[1152 + tid];
            ((unsigned*)XKH)[(size_t)bs * 384 + tid] = pk2(k0, k1);
            ((unsigned*)XVH)[(size_t)bs * 384 + tid] = pk2(v0, v1);
        }
        return;
    }

    // ================= prep blocks (1024 threads) =================
    int id = bx - NBS;
    if (id < 324) {
        // AB[n][k]: n<128 -> a1 col n ; n>=128 -> v1 col n-128  (both 5184x128)
        float (*tile)[65] = (float(*)[65])smem;
        int kt = id % 81, nt = id / 81;
        const float* src = (nt < 2) ? a1 : v1;
        int col0 = (nt & 1) * 64;
        #pragma unroll
        for (int it = 0; it < 4; ++it) {
            int idx = it * 1024 + tid; int ki = idx >> 6, ni = idx & 63;
            tile[ki][ni] = src[(size_t)(kt * 64 + ki) * 128 + col0 + ni];
        }
        __syncthreads();
        #pragma unroll
        for (int it = 0; it < 4; ++it) {
            int idx = it * 1024 + tid; int ni = idx >> 6, ki = idx & 63;
            AB[(size_t)(nt * 64 + ni) * 5184 + kt * 64 + ki] = f2bf(tile[ki][ni]);
        }
    } else if (id < 343) {
        // PH[o][d] = bf16( sum_c sprite[o][c]*Wk[d][c] ), o<25
        int g = (id - 324) * 1024 + tid;
        if (g < 19200) {
            int o = g / 768, d = g - o * 768;
            const float* sp = sprite + o * 256;
            const float* wr = Wk + (size_t)d * 256;
            float s = 0.f;
            for (int cc = 0; cc < 256; ++cc) s += sp[cc] * wr[cc];
            PH[(size_t)o * 768 + d] = f2bf(s);
        }
    } else if (id < 363) {
        // RD[o][n]: o<25 rowdot rows (sprite), o==25 -> bv@W2
        int g = (id - 343) * 1024 + tid;
        if (g < 19968) {
            int o = g / 768, n = g - o * 768;
            int tap = n >> 6, f = n & 63; int t4 = tap / 3, j = tap - t4 * 3;
            const float* sp = (o < 25) ? (sprite + o * 256) : bv;
            float s = 0.f;
            for (int e = 0; e < 256; ++e)
                s += sp[e] * conv_w[(size_t)(t4 * 768 + j * 256 + e) * 64 + f];
            RD[g] = s;
        }
    } else if (id < 507) {
        // WCT[tf][dm] = sum_c W2[tf][c]*Wv[dm][c] (fp32 accum, bf16 out)
        int wid2 = id - 363;
        int bm = (wid2 / 12) * 64, bn = (wid2 % 12) * 64;
        int p = bm >> 6; int t4 = p / 3, jj = p - t4 * 3;
        const float* cwb = conv_w + (size_t)(t4 * 768 + jj * 256) * 64;
        float* As = (float*)smem;            // [32][65]
        float* Bs = (float*)smem + 2080;     // [32][65]
        float acc[4][4];
        #pragma unroll
        for (int i = 0; i < 4; ++i)
            #pragma unroll
            for (int j = 0; j < 4; ++j) acc[i][j] = 0.f;
        int tm = (tid & 255) >> 4, tn = tid & 15;
        for (int kc = 0; kc < 256; kc += 32) {
            for (int idx = tid; idx < 2048; idx += 1024) {
                int cc = idx >> 6, f = idx & 63;
                As[cc * 65 + f] = cwb[(size_t)(kc + cc) * 64 + f];
            }
            for (int idx = tid; idx < 2048; idx += 1024) {
                int d = idx >> 5, cc = idx & 31;
                Bs[cc * 65 + d] = Wv[(size_t)(bn + d) * 256 + kc + cc];
            }
            __syncthreads();
            if (tid < 256) {
                for (int kk = 0; kk < 32; ++kk) {
                    float a[4], b[4];
                    #pragma unroll
                    for (int i = 0; i < 4; ++i) a[i] = As[kk * 65 + tm * 4 + i];
                    #pragma unroll
                    for (int j = 0; j < 4; ++j) b[j] = Bs[kk * 65 + tn * 4 + j];
                    #pragma unroll
                    for (int i = 0; i < 4; ++i)
                        #pragma unroll
                        for (int j = 0; j < 4; ++j) acc[i][j] += a[i] * b[j];
                }
            }
            __syncthreads();
        }
        if (tid < 256) {
            #pragma unroll
            for (int i = 0; i < 4; ++i)
                #pragma unroll
                for (int j = 0; j < 4; ++j)
                    WCT[(size_t)(bm + tm * 4 + i) * 768 + bn + tn * 4 + j] = f2bf(acc[i][j]);
        }
    } else {
        if (tid < 25) {
            float s = 0.f;
            for (int cc = 0; cc < 256; ++cc) s += sprite[tid * 256 + cc];
            FL[tid] = (s != 0.0f) ? 1 : 0;
        }
    }
}

// ======== k3: fused VW gemm (by<12) + DT gemm (by==12), K=768 ================
__global__ __launch_bounds__(256) void k3_vwdt(
    const short* __restrict__ XVH, const short* __restrict__ WCT,
    const float* __restrict__ bvW2, short* __restrict__ VWH,
    const short* __restrict__ XKH, const short* __restrict__ PH,
    float* __restrict__ DT)
{
    __shared__ short As[64][40];
    __shared__ short Bs[64][40];
    int tid = threadIdx.x;
    bool isdt = (blockIdx.y == 12);
    const short* A = isdt ? XKH : XVH;
    const short* B = isdt ? PH  : WCT;
    int bm = blockIdx.x * 64, bn = isdt ? 0 : blockIdx.y * 64;
    int wid = tid >> 6, lane = tid & 63;
    int wm = (wid >> 1) * 32, wn = (wid & 1) * 32;
    int l15 = lane & 15, lg = lane >> 4;

    f32x4 zero = {0.f, 0.f, 0.f, 0.f};
    f32x4 acc00 = zero, acc01 = zero, acc10 = zero, acc11 = zero;

    int srow = tid >> 2, kch = (tid & 3) * 8;
    const short* Ap = A + (size_t)(bm + srow) * 768 + kch;
    const short* Bp = B + (size_t)(bn + srow) * 768 + kch;

    for (int kt = 0; kt < 768; kt += 32) {
        bf16x8 aval = *(const bf16x8*)(Ap + kt);
        bf16x8 bval = *(const bf16x8*)(Bp + kt);
        *(bf16x8*)&As[srow][kch] = aval;
        *(bf16x8*)&Bs[srow][kch] = bval;
        __syncthreads();
        bf16x8 af0 = *(const bf16x8*)&As[wm + l15][lg * 8];
        bf16x8 af1 = *(const bf16x8*)&As[wm + 16 + l15][lg * 8];
        bf16x8 bg0 = *(const bf16x8*)&Bs[wn + l15][lg * 8];
        bf16x8 bg1 = *(const bf16x8*)&Bs[wn + 16 + l15][lg * 8];
        acc00 = __builtin_amdgcn_mfma_f32_16x16x32_bf16(af0, bg0, acc00, 0, 0, 0);
        acc01 = __builtin_amdgcn_mfma_f32_16x16x32_bf16(af0, bg1, acc01, 0, 0, 0);
        acc10 = __builtin_amdgcn_mfma_f32_16x16x32_bf16(af1, bg0, acc10, 0, 0, 0);
        acc11 = __builtin_amdgcn_mfma_f32_16x16x32_bf16(af1, bg1, acc11, 0, 0, 0);
        __syncthreads();
    }

    #pragma unroll
    for (int i = 0; i < 2; ++i) {
        f32x4 arow0 = (i == 0) ? acc00 : acc10;
        f32x4 arow1 = (i == 0) ? acc01 : acc11;
        #pragma unroll
        for (int j = 0; j < 2; ++j) {
            f32x4 a = (j == 0) ? arow0 : arow1;
            int col = bn + wn + j * 16 + l15;
            #pragma unroll
            for (int r = 0; r < 4; ++r) {
                int row = bm + wm + i * 16 + lg * 4 + r;
                if (isdt) DT[(size_t)row * 64 + col] = a[r];
                else      VWH[(size_t)row * 768 + col] = f2bf(a[r] + bvW2[col]);
            }
        }
    }
}

// ---------------- generic MFMA bf16 GEMM: A[M][K] rm, B[N][K] K-major --------
template<int BIAS, int OUTBF>
__global__ __launch_bounds__(256) void gemm_mfma(
    const short* __restrict__ A, const short* __restrict__ B,
    const float* __restrict__ bias, void* __restrict__ Cout,
    int K, int ldc, int klen, size_t czstride)
{
    __shared__ short As[64][40];
    __shared__ short Bs[64][40];
    int tid = threadIdx.x;
    int bm = blockIdx.x * 64, bn = blockIdx.y * 64;
    int wid = tid >> 6, lane = tid & 63;
    int wm = (wid >> 1) * 32, wn = (wid & 1) * 32;
    int l15 = lane & 15, lg = lane >> 4;

    f32x4 zero = {0.f, 0.f, 0.f, 0.f};
    f32x4 acc00 = zero, acc01 = zero, acc10 = zero, acc11 = zero;

    int srow = tid >> 2, kch = (tid & 3) * 8;
    const short* Ap = A + (size_t)(bm + srow) * K + kch + (size_t)blockIdx.z * klen;
    const short* Bp = B + (size_t)(bn + srow) * K + kch + (size_t)blockIdx.z * klen;

    for (int kt = 0; kt < klen; kt += 32) {
        bf16x8 aval = *(const bf16x8*)(Ap + kt);
        bf16x8 bval = *(const bf16x8*)(Bp + kt);
        *(bf16x8*)&As[srow][kch] = aval;
        *(bf16x8*)&Bs[srow][kch] = bval;
        __syncthreads();
        bf16x8 af0 = *(const bf16x8*)&As[wm + l15][lg * 8];
        bf16x8 af1 = *(const bf16x8*)&As[wm + 16 + l15][lg * 8];
        bf16x8 bg0 = *(const bf16x8*)&Bs[wn + l15][lg * 8];
        bf16x8 bg1 = *(const bf16x8*)&Bs[wn + 16 + l15][lg * 8];
        acc00 = __builtin_amdgcn_mfma_f32_16x16x32_bf16(af0, bg0, acc00, 0, 0, 0);
        acc01 = __builtin_amdgcn_mfma_f32_16x16x32_bf16(af0, bg1, acc01, 0, 0, 0);
        acc10 = __builtin_amdgcn_mfma_f32_16x16x32_bf16(af1, bg0, acc10, 0, 0, 0);
        acc11 = __builtin_amdgcn_mfma_f32_16x16x32_bf16(af1, bg1, acc11, 0, 0, 0);
        __syncthreads();
    }

    float* Cf = (float*)Cout + (size_t)blockIdx.z * czstride;
    short* Ch = (short*)Cout;
    #pragma unroll
    for (int i = 0; i < 2; ++i) {
        f32x4 arow0 = (i == 0) ? acc00 : acc10;
        f32x4 arow1 = (i == 0) ? acc01 : acc11;
        #pragma unroll
        for (int j = 0; j < 2; ++j) {
            f32x4 a = (j == 0) ? arow0 : arow1;
            int col = bn + wn + j * 16 + l15;
            float bb = BIAS ? bias[col] : 0.f;
            #pragma unroll
            for (int r = 0; r < 4; ++r) {
                int row = bm + wm + i * 16 + lg * 4 + r;
                float v = a[r] + bb;
                if (OUTBF) Ch[(size_t)row * ldc + col] = f2bf(v);
                else       Cf[(size_t)row * ldc + col] = v;
            }
        }
    }
}

// ======== k4: wts + factored conv + transpose-flatten + lrelu ================
__global__ __launch_bounds__(512) void k4_y(
    const int* __restrict__ state, const float* __restrict__ dt,
    const int* __restrict__ flags, const short* __restrict__ VWH,
    const float* __restrict__ rowdot, const float* __restrict__ conv_b,
    short* __restrict__ y)
{
    int b = blockIdx.x, tid = threadIdx.x;
    __shared__ float s_vW[3 * 768];
    __shared__ float s_w[3][NPOS + 4];
    __shared__ int   s_avt[NPOS + 4];
    __shared__ float s_y[81 * 65];

    const unsigned* vr = (const unsigned*)(VWH + (size_t)b * 3 * 768);
    for (int i = tid; i < 1152; i += 512) {
        unsigned u = vr[i];
        s_vW[2 * i]     = bf2f_lo(u);
        s_vW[2 * i + 1] = bf2f_hi(u);
    }

    for (int code = tid; code < NPOS; code += 512) {
        const int* st = state + ((size_t)b * NPOS + code) * 4;
        int o0 = st[0], o1 = st[1], o2 = st[2], avi = st[3];
        int cnt = flags[o0] + flags[o1] + flags[o2];
        s_avt[code] = avi;
        float w0 = 0.f, w1 = 0.f, w2 = 0.f;
        if (cnt > 0) {
            const float* d0 = dt + (size_t)b * 192;   // [3][64]
            float inv = 1.0f / (16.0f * (float)cnt);
            float q0 = (d0[o0]       + d0[o1]       + d0[o2])       * inv;
            float q1 = (d0[64 + o0]  + d0[64 + o1]  + d0[64 + o2])  * inv;
            float q2 = (d0[128 + o0] + d0[128 + o1] + d0[128 + o2]) * inv;
            float m = fmaxf(q0, fmaxf(q1, q2));
            float e0 = expf(q0 - m), e1 = expf(q1 - m), e2 = expf(q2 - m);
            float is = 1.0f / (6.0f * (e0 + e1 + e2));   // folds att/3 and st/2
            w0 = e0 * is; w1 = e1 * is; w2 = e2 * is;
        }
        s_w[0][code] = w0; s_w[1][code] = w1; s_w[2][code] = w2;
    }
    __syncthreads();

    int f = tid & 63;
    float cb = conv_b[f];
    for (int p = tid >> 6; p < 81; p += 8) {
        int oh = p / 9, ow = p - oh * 9;
        float acc = cb;
        #pragma unroll
        for (int kh = 0; kh < 2; ++kh)
        #pragma unroll
        for (int kw = 0; kw < 2; ++kw) {
            int bc = 3 * ((oh + kh) * 10 + (ow + kw));
            int tbase = ((kh * 2 + kw) * 3) * 64 + f;
            #pragma unroll
            for (int j = 0; j < 3; ++j) {
                int code = bc + j;
                int tf = tbase + j * 64;
                acc += s_w[0][code] * s_vW[tf]
                     + s_w[1][code] * s_vW[768 + tf]
                     + s_w[2][code] * s_vW[2 * 768 + tf];
                acc += 0.5f * rowdot[(size_t)s_avt[code] * 768 + tf];
            }
        }
        acc = acc > 0.f ? acc : 0.01f * acc;
        s_y[p * 65 + f] = acc;
    }
    __syncthreads();
    for (int i = tid; i < LIN; i += 512) {
        int ff = i / 81, pp = i - ff * 81;
        y[(size_t)b * LIN + i] = f2bf(s_y[pp * 65 + ff]);
    }
}

// ======== k6: split-K reduce + layer2 + heads ================================
__global__ __launch_bounds__(128) void k6_heads(
    const float* __restrict__ PART, const float* __restrict__ a1b,
    const float* __restrict__ v1b, const int* __restrict__ action,
    const float* __restrict__ a2, const float* __restrict__ a2b,
    const float* __restrict__ a3, const float* __restrict__ a3b,
    const float* __restrict__ v2, const float* __restrict__ v2b,
    const float* __restrict__ v3, const float* __restrict__ v3b,
    float* __restrict__ out)
{
    int b = blockIdx.x, tid = threadIdx.x;
    __shared__ float h1a[128], h1v[128], h2a[128], red[128];
    __shared__ float lg[5];
    float sa0 = a1b[tid], sv0 = v1b[tid];
    const float* pb = PART + (size_t)b * 256;
    for (int z = 0; z < KSPLIT; ++z) {
        sa0 += pb[(size_t)z * (BS * 256) + tid];
        sv0 += pb[(size_t)z * (BS * 256) + 128 + tid];
    }
    h1a[tid] = sa0 > 0.f ? sa0 : 0.01f * sa0;
    h1v[tid] = sv0 > 0.f ? sv0 : 0.01f * sv0;
    __syncthreads();
    float sa = a2b[tid], sv = v2b[tid];
    for (int k = 0; k < 128; ++k) {
        sa += h1a[k] * a2[k * 128 + tid];
        sv += h1v[k] * v2[k * 128 + tid];
    }
    sa = sa > 0.f ? sa : 0.01f * sa;
    sv = sv > 0.f ? sv : 0.01f * sv;
    h2a[tid] = sa;
    red[tid] = sv * v3[tid];
    __syncthreads();
    for (int s = 64; s > 0; s >>= 1) {
        if (tid < s) red[tid] += red[tid + s];
        __syncthreads();
    }
    if (tid < 5) {
        float l = a3b[tid];
        for (int k = 0; k < 128; ++k) l += h2a[k] * a3[k * 5 + tid];
        lg[tid] = l;
    }
    __syncthreads();
    if (tid == 0) {
        float m = lg[0];
        for (int j2 = 1; j2 < 5; ++j2) m = fmaxf(m, lg[j2]);
        float se = 0.f;
        for (int j2 = 0; j2 < 5; ++j2) se += expf(lg[j2] - m);
        float lse = m + logf(se);
        int act = action[b];
        float ent = 0.f;
        for (int j2 = 0; j2 < 5; ++j2) {
            float lp = lg[j2] - lse;
            ent -= expf(lp) * lp;
        }
        out[b]        = lg[act] - lse;
        out[512 + b]  = red[0] + v3b[0];
        out[1024 + b] = ent;
    }
}

// ---------------- launch ----------------
extern "C" void kernel_launch(void* const* d_in, const int* in_sizes, int n_in,
                              void* d_out, int out_size, void* d_ws, size_t ws_size,
                              hipStream_t stream)
{
    const int*   state  = (const int*)d_in[0];
    const int*   action = (const int*)d_in[1];
    const float* temb   = (const float*)d_in[2];
    const float* sprite = (const float*)d_in[3];
    const float* conv_w = (const float*)d_in[4];
    const float* conv_b = (const float*)d_in[5];
    const float* Wk     = (const float*)d_in[6];
    const float* Wks    = (const float*)d_in[8];
    const float* Wv     = (const float*)d_in[10];
    const float* bv     = (const float*)d_in[11];
    const float* Wvs    = (const float*)d_in[12];
    const float* a1     = (const float*)d_in[14];
    const float* a1b    = (const float*)d_in[15];
    const float* a2     = (const float*)d_in[16];
    const float* a2b    = (const float*)d_in[17];
    const float* a3     = (const float*)d_in[18];
    const float* a3b    = (const float*)d_in[19];
    const float* v1     = (const float*)d_in[20];
    const float* v1b    = (const float*)d_in[21];
    const float* v2     = (const float*)d_in[22];
    const float* v2b    = (const float*)d_in[23];
    const float* v3     = (const float*)d_in[24];
    const float* v3b    = (const float*)d_in[25];
    (void)in_sizes; (void)n_in; (void)out_size; (void)ws_size;

    float* ws  = (float*)d_ws;
    float* RD  = ws + OFF_RD;
    float* bvW2= RD + 25 * 768;
    int*   FL  = (int*)(ws + OFF_FL);
    float* DT  = ws + OFF_DT;
    short* WCT = (short*)(ws + OFF_WCT);
    short* PH  = (short*)(ws + OFF_PH);
    short* AB  = (short*)(ws + OFF_AB);
    short* XKH = (short*)(ws + OFF_XKH);
    short* XVH = (short*)(ws + OFF_XVH);
    short* VWH = (short*)(ws + OFF_VWH);
    short* YH  = (short*)(ws + OFF_YH);
    float* PART= ws + OFF_PART;
    float* out = (float*)d_out;

    // 1) monolithic temb (1024 threads, 2 blocks/CU = 32 waves) + all prep
    k1_fused<<<NBS + 508, 1024, 0, stream>>>(
        temb, Wks, Wvs, conv_w, sprite, Wk, Wv, bv, a1, v1,
        XKH, XVH, AB, PH, WCT, RD, FL);
    // 2) VWH = XVH@WCT^T + bv@W2 (bf16)  ||  DT = XKH@PH^T (fp32)
    k3_vwdt<<<dim3(24,13,1),256,0,stream>>>(XVH, WCT, bvW2, VWH, XKH, PH, DT);
    // 3) conv + flatten
    k4_y<<<BS, 512, 0, stream>>>(state, DT, FL, VWH, RD, conv_b, YH);
    // 4) layer-1 split-K GEMM
    gemm_mfma<0,0><<<dim3(8,4,KSPLIT),256,0,stream>>>(YH, AB, nullptr, PART, 5184, 256, KCH, (size_t)BS*256);
    // 5) reduce + heads
    k6_heads<<<BS, 128, 0, stream>>>(PART, a1b, v1b, action, a2, a2b, a3, a3b,
                                     v2, v2b, v3, v3b, out);
}

// Round 14
// 122.953 us; speedup vs baseline: 1.1942x; 1.1942x over previous
//
#include <hip/hip_runtime.h>
#include <hip/hip_bf16.h>
#include <math.h>

// ---------------- problem constants ----------------
constexpr int BS   = 512;
constexpr int NBS  = 1536;   // BS * NSENT
constexpr int NPOS = 300;    // HIST*H*W
constexpr int LIN  = 5184;   // FM * 9 * 9
constexpr int KSPLIT = 9, KCH = 576;    // 9*576 = 5184

typedef __attribute__((ext_vector_type(8))) short bf16x8;
typedef __attribute__((ext_vector_type(4))) float f32x4;

static __device__ __forceinline__ short f2bf(float f) {
    unsigned u = __float_as_uint(f);
    unsigned r = (u + 0x7FFFu + ((u >> 16) & 1u)) >> 16;
    return (short)r;
}
static __device__ __forceinline__ unsigned pk2(float a, float b) {
    return ((unsigned)(unsigned short)f2bf(a)) | (((unsigned)(unsigned short)f2bf(b)) << 16);
}
static __device__ __forceinline__ float bf2f_lo(unsigned u) { return __uint_as_float(u << 16); }
static __device__ __forceinline__ float bf2f_hi(unsigned u) { return __uint_as_float(u & 0xFFFF0000u); }

#define DOT4(a,b) ((a).x*(b).x + (a).y*(b).y + (a).z*(b).z + (a).w*(b).w)

// ---------------- workspace layout (float offsets) ----------------
constexpr size_t OFF_RD   = 0;         // 26*768 fp32 (0..24 rowdot, 25 = bv@W2)
constexpr size_t OFF_FL   = 19968;     // 64 (int)
constexpr size_t OFF_DT   = 20032;     // fp32 [1536][64]
constexpr size_t OFF_WCT  = 118336;    // bf16 [768][768] -> 294912 floats
constexpr size_t OFF_PH   = 413248;    // bf16 [64][768]  -> 24576
constexpr size_t OFF_AB   = 437824;    // bf16 [256][5184] -> 663552
constexpr size_t OFF_XKH  = 1322560;   // bf16 [1536][768] -> 589824 floats
constexpr size_t OFF_XVH  = 1912384;   // bf16 [1536][768] -> 589824
constexpr size_t OFF_VWH  = 2502208;   // bf16 [1536][768] -> 589824
constexpr size_t OFF_YH   = 3092032;   // bf16 [512][5184] -> 1327104 floats
constexpr size_t OFF_PART = 4419136;   // fp32 [9][512][256]; end 5598784 (~22.4MB)

// ======== k1: monolithic per-(b,s) temb (34-token LDS stage, 3 blocks/CU) ====
// blocks 0..1535 : (b,s): stage tokens 0..33 as bf16 in LDS; tokens 34,35 from
//                  global. scores -> softmax -> weighted sums -> XKH/XVH.
// blocks 1536+   : prep (AB 0..323, PH 324..361, RD 362..400, WCT 401..544, FL 545)
__global__ __launch_bounds__(512) void k1_fused(
    const float* __restrict__ temb, const float* __restrict__ Wks,
    const float* __restrict__ Wvs, const float* __restrict__ conv_w,
    const float* __restrict__ sprite, const float* __restrict__ Wk,
    const float* __restrict__ Wv, const float* __restrict__ bv,
    const float* __restrict__ a1, const float* __restrict__ v1,
    short* __restrict__ XKH, short* __restrict__ XVH,
    short* __restrict__ AB, short* __restrict__ PH, short* __restrict__ WCT,
    float* __restrict__ RD, int* __restrict__ FL)
{
    __shared__ unsigned smem[13056 + 160];   // 34*384 bf16x2 + sco = 52.9KB -> 3 blocks/CU
    unsigned* hbuf = smem;
    float (*sco)[40] = (float(*)[40])(smem + 13056);
    int tid = threadIdx.x, bx = blockIdx.x;
    int w = tid >> 6, lane = tid & 63;

    if (bx < NBS) {
        int bs = bx;
        const f32x4* src4 = (const f32x4*)temb + (size_t)bs * 6912;

        // ---- phase 1: stage tokens 0..33 (6528 float4) as bf16 ----
        #pragma unroll
        for (int c = 0; c < 13; ++c) {
            int i = c * 512 + tid;
            if (c < 12 || i < 6528) {
                f32x4 v = src4[i];
                hbuf[2 * i]     = pk2(v.x, v.y);
                hbuf[2 * i + 1] = pk2(v.z, v.w);
            }
        }
        __syncthreads();

        // ---- phase 2: scores ----
        const float2* wks2 = (const float2*)Wks;
        const float2* wvs2 = (const float2*)Wvs;
        #pragma unroll
        for (int r = 0; r < 4; ++r) {
            int t = w + 8 * r;
            float pk = 0.f, pv = 0.f;
            #pragma unroll
            for (int j = 0; j < 6; ++j) {
                unsigned u = hbuf[t * 384 + lane + 64 * j];
                float x0 = bf2f_lo(u), x1 = bf2f_hi(u);
                float2 a = wks2[lane + 64 * j];
                float2 b = wvs2[lane + 64 * j];
                pk += x0 * a.x + x1 * a.y;
                pv += x0 * b.x + x1 * b.y;
            }
            #pragma unroll
            for (int off = 32; off; off >>= 1) {
                pk += __shfl_down(pk, off);
                pv += __shfl_down(pv, off);
            }
            if (lane == 0) { sco[0][t] = pk; sco[1][t] = pv; }
        }
        if (w < 2) {            // tokens 32,33 from LDS
            int t = 32 + w;
            float pk = 0.f, pv = 0.f;
            #pragma unroll
            for (int j = 0; j < 6; ++j) {
                unsigned u = hbuf[t * 384 + lane + 64 * j];
                float x0 = bf2f_lo(u), x1 = bf2f_hi(u);
                float2 a = wks2[lane + 64 * j];
                float2 b = wvs2[lane + 64 * j];
                pk += x0 * a.x + x1 * a.y;
                pv += x0 * b.x + x1 * b.y;
            }
            #pragma unroll
            for (int off = 32; off; off >>= 1) {
                pk += __shfl_down(pk, off);
                pv += __shfl_down(pv, off);
            }
            if (lane == 0) { sco[0][t] = pk; sco[1][t] = pv; }
        } else if (w < 4) {     // tokens 34,35 from global (fp32)
            int t = 32 + w;
            const f32x4* row = src4 + (size_t)t * 192;
            const f32x4* k4 = (const f32x4*)Wks;
            const f32x4* v4 = (const f32x4*)Wvs;
            float pk = 0.f, pv = 0.f;
            #pragma unroll
            for (int i = 0; i < 3; ++i) {
                f32x4 x = row[lane + 64 * i];
                pk += DOT4(x, k4[lane + 64 * i]);
                pv += DOT4(x, v4[lane + 64 * i]);
            }
            #pragma unroll
            for (int off = 32; off; off >>= 1) {
                pk += __shfl_down(pk, off);
                pv += __shfl_down(pv, off);
            }
            if (lane == 0) { sco[0][t] = pk; sco[1][t] = pv; }
        }
        __syncthreads();

        // ---- phase 3: exact softmax over 36 (waves 0,1 for k,v) ----
        if (w < 2) {
            float s = (lane < 36) ? sco[w][lane] : -INFINITY;
            float m = s;
            #pragma unroll
            for (int off = 32; off; off >>= 1) m = fmaxf(m, __shfl_xor(m, off));
            float e = (lane < 36) ? expf(s - m) : 0.f;
            float z = e;
            #pragma unroll
            for (int off = 32; off; off >>= 1) z += __shfl_xor(z, off);
            if (lane < 36) sco[2 + w][lane] = e / z;
        }
        __syncthreads();

        // ---- phase 4: weighted sums (34 LDS tokens + 2 global tokens) ----
        if (tid < 384) {
            float k0 = 0.f, k1 = 0.f, v0 = 0.f, v1 = 0.f;
            #pragma unroll
            for (int t = 0; t < 34; ++t) {
                unsigned u = hbuf[t * 384 + tid];
                float x0 = bf2f_lo(u), x1 = bf2f_hi(u);
                float wk = sco[2][t], wv = sco[3][t];
                k0 += wk * x0; k1 += wk * x1;
                v0 += wv * x0; v1 += wv * x1;
            }
            const float* rowb = temb + (size_t)bs * 27648;
            float2 g34 = *(const float2*)(rowb + 34 * 768 + 2 * tid);
            float2 g35 = *(const float2*)(rowb + 35 * 768 + 2 * tid);
            k0 += sco[2][34] * g34.x + sco[2][35] * g35.x;
            k1 += sco[2][34] * g34.y + sco[2][35] * g35.y;
            v0 += sco[3][34] * g34.x + sco[3][35] * g35.x;
            v1 += sco[3][34] * g34.y + sco[3][35] * g35.y;
            ((unsigned*)XKH)[(size_t)bs * 384 + tid] = pk2(k0, k1);
            ((unsigned*)XVH)[(size_t)bs * 384 + tid] = pk2(v0, v1);
        }
        return;
    }

    // ================= prep blocks (512 threads) =================
    int id = bx - NBS;
    if (id < 324) {
        // AB[n][k]: n<128 -> a1 col n ; n>=128 -> v1 col n-128  (both 5184x128)
        float (*tile)[65] = (float(*)[65])smem;
        int kt = id % 81, nt = id / 81;
        const float* src = (nt < 2) ? a1 : v1;
        int col0 = (nt & 1) * 64;
        #pragma unroll
        for (int it = 0; it < 8; ++it) {
            int idx = it * 512 + tid; int ki = idx >> 6, ni = idx & 63;
            tile[ki][ni] = src[(size_t)(kt * 64 + ki) * 128 + col0 + ni];
        }
        __syncthreads();
        #pragma unroll
        for (int it = 0; it < 8; ++it) {
            int idx = it * 512 + tid; int ni = idx >> 6, ki = idx & 63;
            AB[(size_t)(nt * 64 + ni) * 5184 + kt * 64 + ki] = f2bf(tile[ki][ni]);
        }
    } else if (id < 362) {
        // PH[o][d] = bf16( sum_c sprite[o][c]*Wk[d][c] ), o<25
        int g = (id - 324) * 512 + tid;
        if (g < 19200) {
            int o = g / 768, d = g - o * 768;
            const float* sp = sprite + o * 256;
            const float* wr = Wk + (size_t)d * 256;
            float s = 0.f;
            for (int c = 0; c < 256; ++c) s += sp[c] * wr[c];
            PH[(size_t)o * 768 + d] = f2bf(s);
        }
    } else if (id < 401) {
        // RD[o][n]: o<25 rowdot rows (sprite), o==25 -> bv@W2
        int g = (id - 362) * 512 + tid;
        if (g < 19968) {
            int o = g / 768, n = g - o * 768;
            int tap = n >> 6, f = n & 63; int t4 = tap / 3, j = tap - t4 * 3;
            const float* sp = (o < 25) ? (sprite + o * 256) : bv;
            float s = 0.f;
            for (int e = 0; e < 256; ++e)
                s += sp[e] * conv_w[(size_t)(t4 * 768 + j * 256 + e) * 64 + f];
            RD[g] = s;
        }
    } else if (id < 545) {
        // WCT[tf][dm] = sum_c W2[tf][c]*Wv[dm][c] (fp32 accum, bf16 out)
        int wid2 = id - 401;
        int bm = (wid2 / 12) * 64, bn = (wid2 % 12) * 64;
        int p = bm >> 6; int t4 = p / 3, jj = p - t4 * 3;
        const float* cwb = conv_w + (size_t)(t4 * 768 + jj * 256) * 64;
        float* As = (float*)smem;            // [32][65]
        float* Bs = (float*)smem + 2080;     // [32][65]
        float acc[4][4];
        #pragma unroll
        for (int i = 0; i < 4; ++i)
            #pragma unroll
            for (int j = 0; j < 4; ++j) acc[i][j] = 0.f;
        int tm = (tid & 255) >> 4, tn = tid & 15;
        for (int kc = 0; kc < 256; kc += 32) {
            for (int idx = tid; idx < 2048; idx += 512) {
                int cc = idx >> 6, f = idx & 63;
                As[cc * 65 + f] = cwb[(size_t)(kc + cc) * 64 + f];
            }
            for (int idx = tid; idx < 2048; idx += 512) {
                int d = idx >> 5, cc = idx & 31;
                Bs[cc * 65 + d] = Wv[(size_t)(bn + d) * 256 + kc + cc];
            }
            __syncthreads();
            if (tid < 256) {
                for (int kk = 0; kk < 32; ++kk) {
                    float a[4], b[4];
                    #pragma unroll
                    for (int i = 0; i < 4; ++i) a[i] = As[kk * 65 + tm * 4 + i];
                    #pragma unroll
                    for (int j = 0; j < 4; ++j) b[j] = Bs[kk * 65 + tn * 4 + j];
                    #pragma unroll
                    for (int i = 0; i < 4; ++i)
                        #pragma unroll
                        for (int j = 0; j < 4; ++j) acc[i][j] += a[i] * b[j];
                }
            }
            __syncthreads();
        }
        if (tid < 256) {
            #pragma unroll
            for (int i = 0; i < 4; ++i)
                #pragma unroll
                for (int j = 0; j < 4; ++j)
                    WCT[(size_t)(bm + tm * 4 + i) * 768 + bn + tn * 4 + j] = f2bf(acc[i][j]);
        }
    } else {
        if (tid < 25) {
            float s = 0.f;
            for (int c = 0; c < 256; ++c) s += sprite[tid * 256 + c];
            FL[tid] = (s != 0.0f) ? 1 : 0;
        }
    }
}

// ======== k3: fused VW gemm (by<12) + DT gemm (by==12), K=768 ================
__global__ __launch_bounds__(256) void k3_vwdt(
    const short* __restrict__ XVH, const short* __restrict__ WCT,
    const float* __restrict__ bvW2, short* __restrict__ VWH,
    const short* __restrict__ XKH, const short* __restrict__ PH,
    float* __restrict__ DT)
{
    __shared__ short As[64][40];
    __shared__ short Bs[64][40];
    int tid = threadIdx.x;
    bool isdt = (blockIdx.y == 12);
    const short* A = isdt ? XKH : XVH;
    const short* B = isdt ? PH  : WCT;
    int bm = blockIdx.x * 64, bn = isdt ? 0 : blockIdx.y * 64;
    int wid = tid >> 6, lane = tid & 63;
    int wm = (wid >> 1) * 32, wn = (wid & 1) * 32;
    int l15 = lane & 15, lg = lane >> 4;

    f32x4 zero = {0.f, 0.f, 0.f, 0.f};
    f32x4 acc00 = zero, acc01 = zero, acc10 = zero, acc11 = zero;

    int srow = tid >> 2, kch = (tid & 3) * 8;
    const short* Ap = A + (size_t)(bm + srow) * 768 + kch;
    const short* Bp = B + (size_t)(bn + srow) * 768 + kch;

    for (int kt = 0; kt < 768; kt += 32) {
        bf16x8 aval = *(const bf16x8*)(Ap + kt);
        bf16x8 bval = *(const bf16x8*)(Bp + kt);
        *(bf16x8*)&As[srow][kch] = aval;
        *(bf16x8*)&Bs[srow][kch] = bval;
        __syncthreads();
        bf16x8 af0 = *(const bf16x8*)&As[wm + l15][lg * 8];
        bf16x8 af1 = *(const bf16x8*)&As[wm + 16 + l15][lg * 8];
        bf16x8 bg0 = *(const bf16x8*)&Bs[wn + l15][lg * 8];
        bf16x8 bg1 = *(const bf16x8*)&Bs[wn + 16 + l15][lg * 8];
        acc00 = __builtin_amdgcn_mfma_f32_16x16x32_bf16(af0, bg0, acc00, 0, 0, 0);
        acc01 = __builtin_amdgcn_mfma_f32_16x16x32_bf16(af0, bg1, acc01, 0, 0, 0);
        acc10 = __builtin_amdgcn_mfma_f32_16x16x32_bf16(af1, bg0, acc10, 0, 0, 0);
        acc11 = __builtin_amdgcn_mfma_f32_16x16x32_bf16(af1, bg1, acc11, 0, 0, 0);
        __syncthreads();
    }

    #pragma unroll
    for (int i = 0; i < 2; ++i) {
        f32x4 arow0 = (i == 0) ? acc00 : acc10;
        f32x4 arow1 = (i == 0) ? acc01 : acc11;
        #pragma unroll
        for (int j = 0; j < 2; ++j) {
            f32x4 a = (j == 0) ? arow0 : arow1;
            int col = bn + wn + j * 16 + l15;
            #pragma unroll
            for (int r = 0; r < 4; ++r) {
                int row = bm + wm + i * 16 + lg * 4 + r;
                if (isdt) DT[(size_t)row * 64 + col] = a[r];
                else      VWH[(size_t)row * 768 + col] = f2bf(a[r] + bvW2[col]);
            }
        }
    }
}

// ---------------- generic MFMA bf16 GEMM: A[M][K] rm, B[N][K] K-major --------
template<int BIAS, int OUTBF>
__global__ __launch_bounds__(256) void gemm_mfma(
    const short* __restrict__ A, const short* __restrict__ B,
    const float* __restrict__ bias, void* __restrict__ Cout,
    int K, int ldc, int klen, size_t czstride)
{
    __shared__ short As[64][40];
    __shared__ short Bs[64][40];
    int tid = threadIdx.x;
    int bm = blockIdx.x * 64, bn = blockIdx.y * 64;
    int wid = tid >> 6, lane = tid & 63;
    int wm = (wid >> 1) * 32, wn = (wid & 1) * 32;
    int l15 = lane & 15, lg = lane >> 4;

    f32x4 zero = {0.f, 0.f, 0.f, 0.f};
    f32x4 acc00 = zero, acc01 = zero, acc10 = zero, acc11 = zero;

    int srow = tid >> 2, kch = (tid & 3) * 8;
    const short* Ap = A + (size_t)(bm + srow) * K + kch + (size_t)blockIdx.z * klen;
    const short* Bp = B + (size_t)(bn + srow) * K + kch + (size_t)blockIdx.z * klen;

    for (int kt = 0; kt < klen; kt += 32) {
        bf16x8 aval = *(const bf16x8*)(Ap + kt);
        bf16x8 bval = *(const bf16x8*)(Bp + kt);
        *(bf16x8*)&As[srow][kch] = aval;
        *(bf16x8*)&Bs[srow][kch] = bval;
        __syncthreads();
        bf16x8 af0 = *(const bf16x8*)&As[wm + l15][lg * 8];
        bf16x8 af1 = *(const bf16x8*)&As[wm + 16 + l15][lg * 8];
        bf16x8 bg0 = *(const bf16x8*)&Bs[wn + l15][lg * 8];
        bf16x8 bg1 = *(const bf16x8*)&Bs[wn + 16 + l15][lg * 8];
        acc00 = __builtin_amdgcn_mfma_f32_16x16x32_bf16(af0, bg0, acc00, 0, 0, 0);
        acc01 = __builtin_amdgcn_mfma_f32_16x16x32_bf16(af0, bg1, acc01, 0, 0, 0);
        acc10 = __builtin_amdgcn_mfma_f32_16x16x32_bf16(af1, bg0, acc10, 0, 0, 0);
        acc11 = __builtin_amdgcn_mfma_f32_16x16x32_bf16(af1, bg1, acc11, 0, 0, 0);
        __syncthreads();
    }

    float* Cf = (float*)Cout + (size_t)blockIdx.z * czstride;
    short* Ch = (short*)Cout;
    #pragma unroll
    for (int i = 0; i < 2; ++i) {
        f32x4 arow0 = (i == 0) ? acc00 : acc10;
        f32x4 arow1 = (i == 0) ? acc01 : acc11;
        #pragma unroll
        for (int j = 0; j < 2; ++j) {
            f32x4 a = (j == 0) ? arow0 : arow1;
            int col = bn + wn + j * 16 + l15;
            float bb = BIAS ? bias[col] : 0.f;
            #pragma unroll
            for (int r = 0; r < 4; ++r) {
                int row = bm + wm + i * 16 + lg * 4 + r;
                float v = a[r] + bb;
                if (OUTBF) Ch[(size_t)row * ldc + col] = f2bf(v);
                else       Cf[(size_t)row * ldc + col] = v;
            }
        }
    }
}

// ======== k4: wts + factored conv + transpose-flatten + lrelu ================
__global__ __launch_bounds__(512) void k4_y(
    const int* __restrict__ state, const float* __restrict__ dt,
    const int* __restrict__ flags, const short* __restrict__ VWH,
    const float* __restrict__ rowdot, const float* __restrict__ conv_b,
    short* __restrict__ y)
{
    int b = blockIdx.x, tid = threadIdx.x;
    __shared__ float s_vW[3 * 768];
    __shared__ float s_w[3][NPOS + 4];
    __shared__ int   s_avt[NPOS + 4];
    __shared__ float s_y[81 * 65];

    const unsigned* vr = (const unsigned*)(VWH + (size_t)b * 3 * 768);
    for (int i = tid; i < 1152; i += 512) {
        unsigned u = vr[i];
        s_vW[2 * i]     = bf2f_lo(u);
        s_vW[2 * i + 1] = bf2f_hi(u);
    }

    for (int code = tid; code < NPOS; code += 512) {
        const int* st = state + ((size_t)b * NPOS + code) * 4;
        int o0 = st[0], o1 = st[1], o2 = st[2], avi = st[3];
        int cnt = flags[o0] + flags[o1] + flags[o2];
        s_avt[code] = avi;
        float w0 = 0.f, w1 = 0.f, w2 = 0.f;
        if (cnt > 0) {
            const float* d0 = dt + (size_t)b * 192;   // [3][64]
            float inv = 1.0f / (16.0f * (float)cnt);
            float q0 = (d0[o0]       + d0[o1]       + d0[o2])       * inv;
            float q1 = (d0[64 + o0]  + d0[64 + o1]  + d0[64 + o2])  * inv;
            float q2 = (d0[128 + o0] + d0[128 + o1] + d0[128 + o2]) * inv;
            float m = fmaxf(q0, fmaxf(q1, q2));
            float e0 = expf(q0 - m), e1 = expf(q1 - m), e2 = expf(q2 - m);
            float is = 1.0f / (6.0f * (e0 + e1 + e2));   // folds att/3 and st/2
            w0 = e0 * is; w1 = e1 * is; w2 = e2 * is;
        }
        s_w[0][code] = w0; s_w[1][code] = w1; s_w[2][code] = w2;
    }
    __syncthreads();

    int f = tid & 63;
    float cb = conv_b[f];
    for (int p = tid >> 6; p < 81; p += 8) {
        int oh = p / 9, ow = p - oh * 9;
        float acc = cb;
        #pragma unroll
        for (int kh = 0; kh < 2; ++kh)
        #pragma unroll
        for (int kw = 0; kw < 2; ++kw) {
            int bc = 3 * ((oh + kh) * 10 + (ow + kw));
            int tbase = ((kh * 2 + kw) * 3) * 64 + f;
            #pragma unroll
            for (int j = 0; j < 3; ++j) {
                int code = bc + j;
                int tf = tbase + j * 64;
                acc += s_w[0][code] * s_vW[tf]
                     + s_w[1][code] * s_vW[768 + tf]
                     + s_w[2][code] * s_vW[2 * 768 + tf];
                acc += 0.5f * rowdot[(size_t)s_avt[code] * 768 + tf];
            }
        }
        acc = acc > 0.f ? acc : 0.01f * acc;
        s_y[p * 65 + f] = acc;
    }
    __syncthreads();
    for (int i = tid; i < LIN; i += 512) {
        int ff = i / 81, pp = i - ff * 81;
        y[(size_t)b * LIN + i] = f2bf(s_y[pp * 65 + ff]);
    }
}

// ======== k6: split-K reduce + layer2 + heads ================================
__global__ __launch_bounds__(128) void k6_heads(
    const float* __restrict__ PART, const float* __restrict__ a1b,
    const float* __restrict__ v1b, const int* __restrict__ action,
    const float* __restrict__ a2, const float* __restrict__ a2b,
    const float* __restrict__ a3, const float* __restrict__ a3b,
    const float* __restrict__ v2, const float* __restrict__ v2b,
    const float* __restrict__ v3, const float* __restrict__ v3b,
    float* __restrict__ out)
{
    int b = blockIdx.x, tid = threadIdx.x;
    __shared__ float h1a[128], h1v[128], h2a[128], red[128];
    __shared__ float lg[5];
    float sa0 = a1b[tid], sv0 = v1b[tid];
    const float* pb = PART + (size_t)b * 256;
    for (int z = 0; z < KSPLIT; ++z) {
        sa0 += pb[(size_t)z * (BS * 256) + tid];
        sv0 += pb[(size_t)z * (BS * 256) + 128 + tid];
    }
    h1a[tid] = sa0 > 0.f ? sa0 : 0.01f * sa0;
    h1v[tid] = sv0 > 0.f ? sv0 : 0.01f * sv0;
    __syncthreads();
    float sa = a2b[tid], sv = v2b[tid];
    for (int k = 0; k < 128; ++k) {
        sa += h1a[k] * a2[k * 128 + tid];
        sv += h1v[k] * v2[k * 128 + tid];
    }
    sa = sa > 0.f ? sa : 0.01f * sa;
    sv = sv > 0.f ? sv : 0.01f * sv;
    h2a[tid] = sa;
    red[tid] = sv * v3[tid];
    __syncthreads();
    for (int s = 64; s > 0; s >>= 1) {
        if (tid < s) red[tid] += red[tid + s];
        __syncthreads();
    }
    if (tid < 5) {
        float l = a3b[tid];
        for (int k = 0; k < 128; ++k) l += h2a[k] * a3[k * 5 + tid];
        lg[tid] = l;
    }
    __syncthreads();
    if (tid == 0) {
        float m = lg[0];
        for (int j2 = 1; j2 < 5; ++j2) m = fmaxf(m, lg[j2]);
        float se = 0.f;
        for (int j2 = 0; j2 < 5; ++j2) se += expf(lg[j2] - m);
        float lse = m + logf(se);
        int act = action[b];
        float ent = 0.f;
        for (int j2 = 0; j2 < 5; ++j2) {
            float lp = lg[j2] - lse;
            ent -= expf(lp) * lp;
        }
        out[b]        = lg[act] - lse;
        out[512 + b]  = red[0] + v3b[0];
        out[1024 + b] = ent;
    }
}

// ---------------- launch ----------------
extern "C" void kernel_launch(void* const* d_in, const int* in_sizes, int n_in,
                              void* d_out, int out_size, void* d_ws, size_t ws_size,
                              hipStream_t stream)
{
    const int*   state  = (const int*)d_in[0];
    const int*   action = (const int*)d_in[1];
    const float* temb   = (const float*)d_in[2];
    const float* sprite = (const float*)d_in[3];
    const float* conv_w = (const float*)d_in[4];
    const float* conv_b = (const float*)d_in[5];
    const float* Wk     = (const float*)d_in[6];
    const float* Wks    = (const float*)d_in[8];
    const float* Wv     = (const float*)d_in[10];
    const float* bv     = (const float*)d_in[11];
    const float* Wvs    = (const float*)d_in[12];
    const float* a1     = (const float*)d_in[14];
    const float* a1b    = (const float*)d_in[15];
    const float* a2     = (const float*)d_in[16];
    const float* a2b    = (const float*)d_in[17];
    const float* a3     = (const float*)d_in[18];
    const float* a3b    = (const float*)d_in[19];
    const float* v1     = (const float*)d_in[20];
    const float* v1b    = (const float*)d_in[21];
    const float* v2     = (const float*)d_in[22];
    const float* v2b    = (const float*)d_in[23];
    const float* v3     = (const float*)d_in[24];
    const float* v3b    = (const float*)d_in[25];
    (void)in_sizes; (void)n_in; (void)out_size; (void)ws_size;

    float* ws  = (float*)d_ws;
    float* RD  = ws + OFF_RD;
    float* bvW2= RD + 25 * 768;
    int*   FL  = (int*)(ws + OFF_FL);
    float* DT  = ws + OFF_DT;
    short* WCT = (short*)(ws + OFF_WCT);
    short* PH  = (short*)(ws + OFF_PH);
    short* AB  = (short*)(ws + OFF_AB);
    short* XKH = (short*)(ws + OFF_XKH);
    short* XVH = (short*)(ws + OFF_XVH);
    short* VWH = (short*)(ws + OFF_VWH);
    short* YH  = (short*)(ws + OFF_YH);
    float* PART= ws + OFF_PART;
    float* out = (float*)d_out;

    // 1) monolithic temb (34-token LDS stage, 3 blocks/CU) + all prep
    k1_fused<<<NBS + 546, 512, 0, stream>>>(
        temb, Wks, Wvs, conv_w, sprite, Wk, Wv, bv, a1, v1,
        XKH, XVH, AB, PH, WCT, RD, FL);
    // 2) VWH = XVH@WCT^T + bv@W2 (bf16)  ||  DT = XKH@PH^T (fp32)
    k3_vwdt<<<dim3(24,13,1),256,0,stream>>>(XVH, WCT, bvW2, VWH, XKH, PH, DT);
    // 3) conv + flatten
    k4_y<<<BS, 512, 0, stream>>>(state, DT, FL, VWH, RD, conv_b, YH);
    // 4) layer-1 split-K GEMM
    gemm_mfma<0,0><<<dim3(8,4,KSPLIT),256,0,stream>>>(YH, AB, nullptr, PART, 5184, 256, KCH, (size_t)BS*256);
    // 5) reduce + heads
    k6_heads<<<BS, 128, 0, stream>>>(PART, a1b, v1b, action, a2, a2b, a3, a3b,
                                     v2, v2b, v3, v3b, out);
}